// Round 9
// baseline (506.494 us; speedup 1.0000x reference)
//
#include <hip/hip_runtime.h>
#include <cstdint>
#include <cstddef>

#define CIN     16
#define CHID    16
#define T_DIM   31
#define HW_     16384            // 128*128
#define CH_STRIDE 507904         // 31*128*128
#define TILE_W  32
#define SW      34               // TILE_W + 2
#define SPOS    102              // 3 rows x 34 cols
#define PSTR    24               // shorts/position: 48B -> col*48 is 16B-aligned => ds_read_b128
#define SLICE_SH (SPOS * PSTR)   // 2448 shorts = 4896 B
#define NSLOT   4                // 19,584 B LDS ring per 1-wave block

typedef short bf16x8 __attribute__((ext_vector_type(8)));
typedef float f32x16 __attribute__((ext_vector_type(16)));

__device__ __forceinline__ unsigned bf16_bits(float x) {
  unsigned u = __builtin_bit_cast(unsigned, x);
  u += 0x7FFFu + ((u >> 16) & 1u);
  return u >> 16;
}
__device__ __forceinline__ unsigned cvt_pk_bf16(float lo, float hi) {
  unsigned r;
  asm("v_cvt_pk_bf16_f32 %0, %1, %2" : "=v"(r) : "v"(lo), "v"(hi));
  return r;
}

__global__ __launch_bounds__(64, 2)
void qrnn3d_v9(const float* __restrict__ in, const float* __restrict__ Wg,
               const float* __restrict__ bg, float* __restrict__ out) {
  __shared__ __align__(16) short xs[NSLOT][SLICE_SH];

  const int lane = threadIdx.x;
  const int wg   = blockIdx.x;
  // XCD-chunked swizzle: XCD k gets 256 consecutive lin -> contiguous h-rows
  const int lin  = ((wg & 7) << 8) | (wg >> 3);
  const int b    = lin >> 9;               // 4 batches
  const int rr   = lin & 511;              // 128 rows x 4 w-tiles
  const int h    = rr >> 2;
  const int w0   = (rr & 3) * TILE_W;

  const int col  = lane & 31;              // MFMA N column / w offset
  const int half = lane >> 5;              // K half (ci 0-7 / 8-15)

  // ---- weights -> 27 A-frags (one-time, L2-cached) ----
  bf16x8 wfrag[27];
#pragma unroll
  for (int tau = 0; tau < 27; ++tau) {
    bf16x8 f;
#pragma unroll
    for (int j = 0; j < 8; ++j)
      f[j] = (short)bf16_bits(Wg[col * 432 + (half * 8 + j) * 27 + tau]);
    wfrag[tau] = f;
  }

  // ---- bias-preloaded accumulator template + t-invariant store offsets ----
  f32x16 accInit;
  int voff[8];
#pragma unroll
  for (int r = 0; r < 8; ++r) {
    int oc = (r & 3) + 8 * (r >> 2) + 4 * half;   // 0..15
    accInit[r]     = bg[oc];
    accInit[r + 8] = bg[oc + 16];
    voff[r] = (b * CHID + oc) * CH_STRIDE + h * 128 + (w0 + col);
  }

  // ---- staging geometry (t-invariant): unit = (pos, ci-quad), 7 units/lane ----
  const float* gbase = in + (size_t)b * CIN * CH_STRIDE;
  unsigned osp[7];   // dword offset from gbase + tz*HW_
  int  lwb[7];       // LDS short offset within slot
  unsigned msk[7];
  bool stv[7];
#pragma unroll
  for (int i = 0; i < 7; ++i) {
    int g   = lane + i * 64;         // [0,448)
    int c4  = g & 3;
    int pos = g >> 2;                // [0,112)
    stv[i]  = (pos < SPOS);
    int row = pos / SW, cw = pos - row * SW;
    int gh  = h + row - 1, gw = w0 + cw - 1;
    bool ok = stv[i] && ((unsigned)gh < 128u) && ((unsigned)gw < 128u);
    osp[i]  = (unsigned)(c4 * 4 * CH_STRIDE + (ok ? gh * 128 + gw : 0));
    lwb[i]  = pos * PSTR + c4 * 4;
    msk[i]  = ok ? 0xFFFFFFFFu : 0u;
  }

#define LOADV(TZ, vv) do {                                                  \
    if ((TZ) <= 30) {                                                       \
      const float* bt_ = gbase + (TZ) * HW_;                                \
      _Pragma("unroll") for (int i_ = 0; i_ < 7; ++i_) {                    \
        _Pragma("unroll") for (int k_ = 0; k_ < 4; ++k_)                    \
          vv[i_][k_] = bt_[osp[i_] + k_ * CH_STRIDE];                       \
      }                                                                     \
    } else {                                                                \
      _Pragma("unroll") for (int i_ = 0; i_ < 7; ++i_) {                    \
        _Pragma("unroll") for (int k_ = 0; k_ < 4; ++k_) vv[i_][k_] = 0.0f; \
      }                                                                     \
    }                                                                       \
  } while (0)

#define STOREV(vv, SLOT) do {                                               \
    short* dp_ = &xs[(SLOT)][0];                                            \
    _Pragma("unroll") for (int i_ = 0; i_ < 7; ++i_) {                      \
      if (stv[i_]) {                                                        \
        uint2 u_;                                                           \
        u_.x = cvt_pk_bf16(vv[i_][0], vv[i_][1]) & msk[i_];                 \
        u_.y = cvt_pk_bf16(vv[i_][2], vv[i_][3]) & msk[i_];                 \
        *reinterpret_cast<uint2*>(dp_ + lwb[i_]) = u_;                      \
      }                                                                     \
    }                                                                       \
  } while (0)

  const int lrd = col * PSTR + half * 8;   // per-lane LDS read base (shorts)

#define RD(SP, U) (*(const bf16x8*)((SP) + lrd + (((U) / 3) * SW + ((U) % 3)) * PSTR))

  const float C_TANH = 2.8853900817779268f;   // 2*log2(e)
  const float C_SIG  = 1.4426950408889634f;   // log2(e)

  float hst[8];
#pragma unroll
  for (int r = 0; r < 8; ++r) hst[r] = 0.0f;

  auto compute = [&](int t) {
    const short* sA = &xs[(t + 3) & 3][0];   // slice t-1
    const short* sB = &xs[(t    ) & 3][0];   // slice t
    const short* sC = &xs[(t + 1) & 3][0];   // slice t+1

    f32x16 acc1;
#pragma unroll
    for (int i = 0; i < 16; ++i) acc1[i] = 0.0f;
    bf16x8 x0 = RD(sA, 0);
    f32x16 acc0 = __builtin_amdgcn_mfma_f32_32x32x16_bf16(wfrag[0], x0, accInit, 0, 0, 0);
#pragma unroll
    for (int u = 1; u < 9; ++u) {
      bf16x8 xb = RD(sA, u);
      if (u & 1) acc1 = __builtin_amdgcn_mfma_f32_32x32x16_bf16(wfrag[u], xb, acc1, 0, 0, 0);
      else       acc0 = __builtin_amdgcn_mfma_f32_32x32x16_bf16(wfrag[u], xb, acc0, 0, 0, 0);
    }
#pragma unroll
    for (int u = 0; u < 9; ++u) {
      bf16x8 xb = RD(sB, u);
      if ((9 + u) & 1) acc1 = __builtin_amdgcn_mfma_f32_32x32x16_bf16(wfrag[9 + u], xb, acc1, 0, 0, 0);
      else             acc0 = __builtin_amdgcn_mfma_f32_32x32x16_bf16(wfrag[9 + u], xb, acc0, 0, 0, 0);
    }
#pragma unroll
    for (int u = 0; u < 9; ++u) {
      bf16x8 xb = RD(sC, u);
      if ((18 + u) & 1) acc1 = __builtin_amdgcn_mfma_f32_32x32x16_bf16(wfrag[18 + u], xb, acc1, 0, 0, 0);
      else              acc0 = __builtin_amdgcn_mfma_f32_32x32x16_bf16(wfrag[18 + u], xb, acc0, 0, 0, 0);
    }

    float* outT = out + (size_t)t * HW_;
#pragma unroll
    for (int r = 0; r < 8; ++r) {
      float zg = acc0[r] + acc1[r];
      float fg = acc0[r + 8] + acc1[r + 8];
      float ez = exp2f(zg * C_TANH);
      float z  = __builtin_fmaf(-2.0f, __builtin_amdgcn_rcpf(ez + 1.0f), 1.0f);
      float ef = exp2f(-fg * C_SIG);
      float f  = __builtin_amdgcn_rcpf(1.0f + ef);
      float hh = __builtin_fmaf(f, hst[r] - z, z);
      hst[r]   = hh;
      outT[voff[r]] = hh;
    }
  };

  // ---- prologue (wave-private: no barriers anywhere) ----
  float vA[7][4], vB[7][4];
  LOADV(0, vA); STOREV(vA, 0);
  LOADV(1, vA); STOREV(vA, 1);
  LOADV(2, vA);                       // slice 2 in regs
  {
    unsigned* zp = (unsigned*)&xs[3][0];
    for (int i = lane; i < SLICE_SH / 2; i += 64) zp[i] = 0u;   // slice -1 = zeros
  }

  // ---- main loop: ping-pong staging, zero barriers ----
#pragma unroll 1
  for (int t = 0; t < 30; t += 2) {
    // even: vA holds slice t+2
    LOADV(t + 3, vB);                 // issue next loads first (hide HBM latency)
    STOREV(vA, (t + 2) & 3);
    compute(t);
    // odd: vB holds slice t+3
    LOADV(t + 4, vA);
    STOREV(vB, (t + 3) & 3);
    compute(t + 1);
  }
  compute(30);

#undef LOADV
#undef STOREV
#undef RD
}

extern "C" void kernel_launch(void* const* d_in, const int* in_sizes, int n_in,
                              void* d_out, int out_size, void* d_ws, size_t ws_size,
                              hipStream_t stream) {
  const float* in = (const float*)d_in[0];
  const float* Wg = (const float*)d_in[1];
  const float* bg = (const float*)d_in[2];
  float* out      = (float*)d_out;
  (void)in_sizes; (void)n_in; (void)out_size; (void)d_ws; (void)ws_size;
  qrnn3d_v9<<<dim3(2048), dim3(64), 0, stream>>>(in, Wg, bg, out);
}

// Round 10
// 260.824 us; speedup vs baseline: 1.9419x; 1.9419x over previous
//
#include <hip/hip_runtime.h>
#include <cstdint>
#include <cstddef>

#define CIN     16
#define CHID    16
#define T_DIM   31
#define HW_     16384            // 128*128
#define CH_STRIDE 507904         // 31*128*128
#define TILE_H  8
#define TILE_W  32
#define SH      10               // TILE_H + 2
#define SW      34               // TILE_W + 2
#define SPOS    (SH * SW)        // 340 positions
#define PSTR    20               // shorts per position (40B: 2-way bank alias = free)
#define SLICE_SH (SPOS * PSTR)   // 6800 shorts
#define NSLOT   4                // 54,400 B LDS ring

typedef short bf16x8 __attribute__((ext_vector_type(8)));
typedef float f32x16 __attribute__((ext_vector_type(16)));

__device__ __forceinline__ unsigned bf16_bits(float x) {
  unsigned u = __builtin_bit_cast(unsigned, x);
  u += 0x7FFFu + ((u >> 16) & 1u);
  return u >> 16;
}
__device__ __forceinline__ unsigned cvt_pk_bf16(float lo, float hi) {
  unsigned r;
  asm("v_cvt_pk_bf16_f32 %0, %1, %2" : "=v"(r) : "v"(lo), "v"(hi));
  return r;
}

__global__ __launch_bounds__(512, 2)
void qrnn3d_v10(const float* __restrict__ in, const float* __restrict__ Wg,
                const float* __restrict__ bg, float* __restrict__ out) {
  __shared__ __align__(16) short xs[NSLOT][SLICE_SH];

  const int tid = threadIdx.x;
  const int bid = blockIdx.x;
  // bijective XCD-chunked swizzle (256 blocks, 256%8==0): XCD k gets 32
  // consecutive lin = 64 contiguous h-rows of one batch -> L2 halo sharing
  const int lin  = ((bid & 7) << 5) | (bid >> 3);
  const int b    = lin >> 6;                 // 4 batches
  const int tile = lin & 63;                 // 16 h-tiles x 4 w-tiles
  const int h0   = (tile >> 2) * TILE_H;
  const int w0   = (tile & 3) * TILE_W;

  const int lane = tid & 63;
  const int wid  = tid >> 6;                 // wave 0..7 -> output row
  const int col  = lane & 31;                // MFMA N column / oc for A-frag
  const int half = lane >> 5;                // K half (ci 0-7 / 8-15)

  // ---- weights -> 27 A-frags ----
  bf16x8 wfrag[27];
#pragma unroll
  for (int tau = 0; tau < 27; ++tau) {
    bf16x8 f;
#pragma unroll
    for (int j = 0; j < 8; ++j)
      f[j] = (short)bf16_bits(Wg[col * 432 + (half * 8 + j) * 27 + tau]);
    wfrag[tau] = f;
  }

  // ---- bias-preloaded accumulator template + t-invariant store offsets ----
  f32x16 accInit;
  int voff[8];
#pragma unroll
  for (int r = 0; r < 8; ++r) {
    int oc = (r & 3) + 8 * (r >> 2) + 4 * half;          // 0..15
    accInit[r]     = bg[oc];
    accInit[r + 8] = bg[oc + 16];
    voff[r] = (b * CHID + oc) * CH_STRIDE + (h0 + wid) * 128 + (w0 + col);
  }

  // ---- staging precompute (t-invariant): unit = (pos, ci-quad), 3/thread ----
  const float* gp[3];
  int  lso[3];
  bool stv[3], ldv[3];
#pragma unroll
  for (int i = 0; i < 3; ++i) {
    int p   = tid + i * 512;         // [0,1536) covers 340*4=1360 units
    int q   = p & 15;
    int c4  = (p >> 4) & 3;
    int j   = p >> 6;
    int pos = j * 16 + q;            // [0,384)
    stv[i]  = (pos < SPOS);
    int hh  = pos / SW;
    int ww  = pos - hh * SW;
    int gh  = h0 + hh - 1, gw = w0 + ww - 1;
    ldv[i]  = stv[i] && ((unsigned)gh < 128u) && ((unsigned)gw < 128u);
    int sp  = ldv[i] ? (gh * 128 + gw) : 0;
    gp[i]   = in + (size_t)(b * CIN + c4 * 4) * CH_STRIDE + sp;
    lso[i]  = pos * PSTR + c4 * 4;   // shorts
  }

#define LOADV(tz, vv)                                                \
  do {                                                               \
    if ((tz) <= 30) {                                                \
      const int toff = (tz) * HW_;                                   \
      _Pragma("unroll")                                              \
      for (int i = 0; i < 3; ++i) {                                  \
        _Pragma("unroll")                                            \
        for (int k = 0; k < 4; ++k)                                  \
          vv[i][k] = ldv[i] ? gp[i][toff + k * CH_STRIDE] : 0.0f;    \
      }                                                              \
    } else {                                                         \
      _Pragma("unroll")                                              \
      for (int i = 0; i < 3; ++i) {                                  \
        _Pragma("unroll")                                            \
        for (int k = 0; k < 4; ++k) vv[i][k] = 0.0f;                 \
      }                                                              \
    }                                                                \
  } while (0)

#define STOREV(vv, slot)                                             \
  do {                                                               \
    short* dst = &xs[(slot)][0];                                     \
    _Pragma("unroll")                                                \
    for (int i = 0; i < 3; ++i) {                                    \
      if (stv[i]) {                                                  \
        uint2 u;                                                     \
        u.x = cvt_pk_bf16(vv[i][0], vv[i][1]);                       \
        u.y = cvt_pk_bf16(vv[i][2], vv[i][3]);                       \
        *reinterpret_cast<uint2*>(dst + lso[i]) = u;                 \
      }                                                              \
    }                                                                \
  } while (0)

  // ---- compute geometry: 9 LDS read offsets (kh,kw), t-invariant ----
  int lb[9];
#pragma unroll
  for (int kh = 0; kh < 3; ++kh)
#pragma unroll
    for (int kw = 0; kw < 3; ++kw)
      lb[kh * 3 + kw] = ((wid + kh) * SW + (col + kw)) * PSTR + half * 8;

  float hst[8];
#pragma unroll
  for (int r = 0; r < 8; ++r) hst[r] = 0.0f;

  const float C_TANH = 2.8853900817779268f;   // 2*log2(e)
  const float C_SIG  = 1.4426950408889634f;   // log2(e)

  auto compute = [&](int t) {
    const short* base = &xs[0][0];
    const short* sA = base + ((t + 3) & 3) * SLICE_SH;   // slice t-1
    const short* sB = base + ((t    ) & 3) * SLICE_SH;   // slice t
    const short* sC = base + ((t + 1) & 3) * SLICE_SH;   // slice t+1

    f32x16 acc0 = accInit;
    f32x16 acc1;
#pragma unroll
    for (int i = 0; i < 16; ++i) acc1[i] = 0.0f;

#pragma unroll
    for (int kd = 0; kd < 3; ++kd) {
      const short* sp = (kd == 0) ? sA : (kd == 1) ? sB : sC;
#pragma unroll
      for (int u = 0; u < 9; ++u) {
        const int tau = kd * 9 + u;
        bf16x8 xb = *reinterpret_cast<const bf16x8*>(sp + lb[u]);
        if (tau & 1)
          acc1 = __builtin_amdgcn_mfma_f32_32x32x16_bf16(wfrag[tau], xb, acc1, 0, 0, 0);
        else
          acc0 = __builtin_amdgcn_mfma_f32_32x32x16_bf16(wfrag[tau], xb, acc0, 0, 0, 0);
      }
    }

    float* outT = out + (size_t)t * HW_;
#pragma unroll
    for (int r = 0; r < 8; ++r) {
      float zg = acc0[r] + acc1[r];
      float fg = acc0[r + 8] + acc1[r + 8];
      float ez = exp2f(zg * C_TANH);
      float z  = __builtin_fmaf(-2.0f, __builtin_amdgcn_rcpf(ez + 1.0f), 1.0f);
      float ef = exp2f(-fg * C_SIG);
      float f  = __builtin_amdgcn_rcpf(1.0f + ef);
      float h  = __builtin_fmaf(f, hst[r] - z, z);
      hst[r]   = h;
      outT[voff[r]] = h;
    }
  };

  // ---- prologue: slices 0,1 staged; slice 2 in regs; slot3 = zeros (slice -1)
  float vA[3][4], vB[3][4];
  LOADV(0, vA); STOREV(vA, 0);
  LOADV(1, vA); STOREV(vA, 1);
  LOADV(2, vA);
  for (int i = tid; i < SLICE_SH / 2; i += 512)
    reinterpret_cast<unsigned*>(&xs[3][0])[i] = 0u;
  __syncthreads();

#pragma unroll 1
  for (int t = 0; t < 30; t += 2) {
    // even step: regs A hold slice t+2
    LOADV(t + 3, vB);                 // issue loads early
    STOREV(vA, (t + 2) & 3);
    compute(t);
    __syncthreads();
    // odd step: regs B hold slice t+3
    LOADV(t + 4, vA);
    STOREV(vB, (t + 3) & 3);
    compute(t + 1);
    __syncthreads();
  }
  compute(30);

#undef LOADV
#undef STOREV
}

extern "C" void kernel_launch(void* const* d_in, const int* in_sizes, int n_in,
                              void* d_out, int out_size, void* d_ws, size_t ws_size,
                              hipStream_t stream) {
  const float* in = (const float*)d_in[0];
  const float* Wg = (const float*)d_in[1];
  const float* bg = (const float*)d_in[2];
  float* out      = (float*)d_out;
  (void)in_sizes; (void)n_in; (void)out_size; (void)d_ws; (void)ws_size;
  qrnn3d_v10<<<dim3(256), dim3(512), 0, stream>>>(in, Wg, bg, out);
}

// Round 11
// 123.243 us; speedup vs baseline: 4.1097x; 2.1163x over previous
//
#include <hip/hip_runtime.h>
#include <cstdint>
#include <cstddef>

#define CIN     16
#define CHID    16
#define T_DIM   31
#define HW_     16384            // 128*128
#define CH_STRIDE 507904         // 31*128*128
#define TILE_H  4
#define TILE_W  32
#define SH      6                // TILE_H + 2
#define SW      34               // TILE_W + 2
#define SPOS    (SH * SW)        // 204 positions
#define PSTR    24               // shorts per position (48B) — R4 champion value
#define SLICE_SH (SPOS * PSTR)   // 4896 shorts

typedef short bf16x8 __attribute__((ext_vector_type(8)));
typedef float f32x16 __attribute__((ext_vector_type(16)));

__device__ __forceinline__ unsigned bf16_bits(float x) {
  unsigned u = __builtin_bit_cast(unsigned, x);
  u += 0x7FFFu + ((u >> 16) & 1u);
  return u >> 16;
}
__device__ __forceinline__ unsigned cvt_pk_bf16(float lo, float hi) {
  unsigned r;
  asm("v_cvt_pk_bf16_f32 %0, %1, %2" : "=v"(r) : "v"(lo), "v"(hi));
  return r;
}

__global__ __launch_bounds__(256, 2)
void qrnn3d_v11(const float* __restrict__ in, const float* __restrict__ Wg,
                const float* __restrict__ bg, float* __restrict__ out) {
  __shared__ __align__(16) short xs[4][SLICE_SH];   // 39,168 B

  const int tid = threadIdx.x;
  const int bid = blockIdx.x;
  // ONLY change vs R4 (129 us champion): bijective XCD-chunked swizzle.
  // 512 blocks, 512%8==0: XCD k gets lin in [k*64, (k+1)*64) = 16 contiguous
  // h-tiles x 4 w-tiles of one batch -> halo-sharing neighbors share an L2.
  const int lin  = ((bid & 7) << 6) | (bid >> 3);
  const int b    = lin >> 7;                 // 4 batches x 128 tiles
  const int tile = lin & 127;
  const int h0   = (tile >> 2) * TILE_H;     // 32 h-tiles
  const int w0   = (tile & 3) * TILE_W;      // 4 w-tiles

  const int lane = tid & 63;
  const int wid  = tid >> 6;                 // wave 0..3 -> output row
  const int col  = lane & 31;                // MFMA N column / oc for A-frag
  const int half = lane >> 5;                // K half (ci 0-7 / 8-15)

  // ---- weights -> 27 A-frags ----
  bf16x8 wfrag[27];
#pragma unroll
  for (int tau = 0; tau < 27; ++tau) {
    bf16x8 f;
#pragma unroll
    for (int j = 0; j < 8; ++j)
      f[j] = (short)bf16_bits(Wg[col * 432 + (half * 8 + j) * 27 + tau]);
    wfrag[tau] = f;
  }

  // ---- bias-preloaded accumulator template + t-invariant store offsets ----
  f32x16 accInit;
  int voff[8];
#pragma unroll
  for (int r = 0; r < 8; ++r) {
    int oc = (r & 3) + 8 * (r >> 2) + 4 * half;          // 0..15
    accInit[r]     = bg[oc];
    accInit[r + 8] = bg[oc + 16];
    voff[r] = (b * CHID + oc) * CH_STRIDE + (h0 + wid) * 128 + (w0 + col);
  }

  // ---- staging precompute (t-invariant): unit = (pos, ci-quad) ----
  const float* gp[4];
  int  lso[4];
  bool stv[4], ldv[4];
#pragma unroll
  for (int i = 0; i < 4; ++i) {
    int p   = tid + i * 256;         // [0,1024)
    int q   = p & 15;
    int c4  = (p >> 4) & 3;
    int j   = p >> 6;
    int pos = j * 16 + q;            // [0,256)
    stv[i]  = (pos < SPOS);
    int hh  = pos / SW;
    int ww  = pos - hh * SW;
    int gh  = h0 + hh - 1, gw = w0 + ww - 1;
    ldv[i]  = stv[i] && ((unsigned)gh < 128u) && ((unsigned)gw < 128u);
    int sp  = ldv[i] ? (gh * 128 + gw) : 0;
    gp[i]   = in + (size_t)(b * CIN + c4 * 4) * CH_STRIDE + sp;
    lso[i]  = pos * PSTR + c4 * 4;   // shorts
  }

#define LOADV(tz, vv)                                                \
  do {                                                               \
    if ((tz) <= 30) {                                                \
      const int toff = (tz) * HW_;                                   \
      _Pragma("unroll")                                              \
      for (int i = 0; i < 4; ++i) {                                  \
        _Pragma("unroll")                                            \
        for (int k = 0; k < 4; ++k)                                  \
          vv[i][k] = ldv[i] ? gp[i][toff + k * CH_STRIDE] : 0.0f;    \
      }                                                              \
    } else {                                                         \
      _Pragma("unroll")                                              \
      for (int i = 0; i < 4; ++i) {                                  \
        _Pragma("unroll")                                            \
        for (int k = 0; k < 4; ++k) vv[i][k] = 0.0f;                 \
      }                                                              \
    }                                                                \
  } while (0)

#define STOREV(vv, slot)                                             \
  do {                                                               \
    short* dst = &xs[(slot)][0];                                     \
    _Pragma("unroll")                                                \
    for (int i = 0; i < 4; ++i) {                                    \
      if (stv[i]) {                                                  \
        uint2 u;                                                     \
        u.x = cvt_pk_bf16(vv[i][0], vv[i][1]);                       \
        u.y = cvt_pk_bf16(vv[i][2], vv[i][3]);                       \
        *reinterpret_cast<uint2*>(dst + lso[i]) = u;                 \
      }                                                              \
    }                                                                \
  } while (0)

  // ---- compute geometry: 9 LDS read offsets (kh,kw), t-invariant ----
  int lb[9];
#pragma unroll
  for (int kh = 0; kh < 3; ++kh)
#pragma unroll
    for (int kw = 0; kw < 3; ++kw)
      lb[kh * 3 + kw] = ((wid + kh) * SW + (col + kw)) * PSTR + half * 8;

  float hst[8];
#pragma unroll
  for (int r = 0; r < 8; ++r) hst[r] = 0.0f;

  const float C_TANH = 2.8853900817779268f;   // 2*log2(e)
  const float C_SIG  = 1.4426950408889634f;   // log2(e)

  auto compute = [&](int t) {
    const short* base = &xs[0][0];
    const short* sA = base + ((t + 3) & 3) * SLICE_SH;   // slice t-1
    const short* sB = base + ((t    ) & 3) * SLICE_SH;   // slice t
    const short* sC = base + ((t + 1) & 3) * SLICE_SH;   // slice t+1

    f32x16 acc0 = accInit;
    f32x16 acc1;
#pragma unroll
    for (int i = 0; i < 16; ++i) acc1[i] = 0.0f;

#pragma unroll
    for (int kd = 0; kd < 3; ++kd) {
      const short* sp = (kd == 0) ? sA : (kd == 1) ? sB : sC;
#pragma unroll
      for (int u = 0; u < 9; ++u) {
        const int tau = kd * 9 + u;
        bf16x8 xb = *reinterpret_cast<const bf16x8*>(sp + lb[u]);
        if (tau & 1)
          acc1 = __builtin_amdgcn_mfma_f32_32x32x16_bf16(wfrag[tau], xb, acc1, 0, 0, 0);
        else
          acc0 = __builtin_amdgcn_mfma_f32_32x32x16_bf16(wfrag[tau], xb, acc0, 0, 0, 0);
      }
    }

    float* outT = out + (size_t)t * HW_;
#pragma unroll
    for (int r = 0; r < 8; ++r) {
      float zg = acc0[r] + acc1[r];
      float fg = acc0[r + 8] + acc1[r + 8];
      float ez = exp2f(zg * C_TANH);
      float z  = __builtin_fmaf(-2.0f, __builtin_amdgcn_rcpf(ez + 1.0f), 1.0f);
      float ef = exp2f(-fg * C_SIG);
      float f  = __builtin_amdgcn_rcpf(1.0f + ef);
      float h  = __builtin_fmaf(f, hst[r] - z, z);
      hst[r]   = h;
      outT[voff[r]] = h;
    }
  };

  // ---- prologue: slices 0,1 staged; slice 2 in regs; slot3 = zeros (slice -1)
  float vA[4][4], vB[4][4];
  LOADV(0, vA); STOREV(vA, 0);
  LOADV(1, vA); STOREV(vA, 1);
  LOADV(2, vA);
  for (int i = tid; i < SLICE_SH / 2; i += 256)
    reinterpret_cast<unsigned*>(&xs[3][0])[i] = 0u;
  __syncthreads();

#pragma unroll 1
  for (int t = 0; t < 30; t += 2) {
    // even step: regs A hold slice t+2
    LOADV(t + 3, vB);                 // issue loads early
    STOREV(vA, (t + 2) & 3);
    compute(t);
    __syncthreads();
    // odd step: regs B hold slice t+3
    LOADV(t + 4, vA);
    STOREV(vB, (t + 3) & 3);
    compute(t + 1);
    __syncthreads();
  }
  compute(30);

#undef LOADV
#undef STOREV
}

extern "C" void kernel_launch(void* const* d_in, const int* in_sizes, int n_in,
                              void* d_out, int out_size, void* d_ws, size_t ws_size,
                              hipStream_t stream) {
  const float* in = (const float*)d_in[0];
  const float* Wg = (const float*)d_in[1];
  const float* bg = (const float*)d_in[2];
  float* out      = (float*)d_out;
  (void)in_sizes; (void)n_in; (void)out_size; (void)d_ws; (void)ws_size;
  qrnn3d_v11<<<dim3(512), dim3(256), 0, stream>>>(in, Wg, bg, out);
}